// Round 1
// baseline (2760.954 us; speedup 1.0000x reference)
//
#include <hip/hip_runtime.h>
#include <math.h>

#define B_   4
#define S_   2048
#define EIN  256
#define AD   128
#define NH   4
#define HD   32
#define TK   32
#define MTOT (B_ * S_)          /* 8192 rows */
#define SEG  1048576            /* 8192*128 */

#define OFF_PROJ 0
#define OFF_Q    (1 * SEG)
#define OFF_K    (2 * SEG)
#define OFF_V    (3 * SEG)
#define OFF_ATT  (4 * SEG)
#define OFF_T    (5 * SEG)
#define OFF_SB   (6 * SEG)
#define OFF_CAT  (7 * SEG)      /* 2*SEG floats */

__device__ float g_ws[9 * SEG];

// Y[M x 128] = X[M x KD] @ W[128 x KD]^T + b   (M = 8192, N = 128)
template <int KD>
__global__ __launch_bounds__(256)
void lin_kernel(const float* __restrict__ Xext, int xoff,
                const float* __restrict__ W, const float* __restrict__ Bv,
                int yoff)
{
    const float* X = Xext ? Xext : (const float*)(g_ws + xoff);
    float* Y = g_ws + yoff;
    __shared__ float Xs[64][33];
    __shared__ float Ws[64][33];
    const int bm = blockIdx.x * 64;
    const int bn = blockIdx.y * 64;
    const int t  = threadIdx.x;
    const int tx = t & 15, ty = t >> 4;
    float acc[4][4] = {};
    for (int kk = 0; kk < KD; kk += 32) {
        #pragma unroll
        for (int i = 0; i < 8; ++i) {
            int idx = t + i * 256;
            int r = idx >> 5, c = idx & 31;
            Xs[r][c] = X[(size_t)(bm + r) * KD + kk + c];
            Ws[r][c] = W[(size_t)(bn + r) * KD + kk + c];
        }
        __syncthreads();
        #pragma unroll
        for (int kc = 0; kc < 32; ++kc) {
            float a[4], bb[4];
            #pragma unroll
            for (int i = 0; i < 4; ++i) a[i] = Xs[ty * 4 + i][kc];
            #pragma unroll
            for (int j = 0; j < 4; ++j) bb[j] = Ws[tx * 4 + j][kc];
            #pragma unroll
            for (int i = 0; i < 4; ++i)
                #pragma unroll
                for (int j = 0; j < 4; ++j)
                    acc[i][j] = fmaf(a[i], bb[j], acc[i][j]);
        }
        __syncthreads();
    }
    #pragma unroll
    for (int i = 0; i < 4; ++i) {
        int row = bm + ty * 4 + i;
        #pragma unroll
        for (int j = 0; j < 4; ++j) {
            int col = bn + tx * 4 + j;
            Y[(size_t)row * AD + col] = acc[i][j] + Bv[col];
        }
    }
}

// One wave per q-row. Scores in registers (32/lane), exact top-32 via
// repeated wave argmax with lax.top_k tie-break (value desc, index asc).
__global__ __launch_bounds__(256)
void attn_kernel(int qoff, int koff, int voff, int ooff)
{
    const float* Q = g_ws + qoff;
    const float* K = g_ws + koff;
    const float* V = g_ws + voff;
    float* O = g_ws + ooff;

    const int bh   = blockIdx.x;          // 0..15
    const int b    = bh >> 2, h = bh & 3;
    const int wid  = threadIdx.x >> 6;    // 4 waves/block
    const int lane = threadIdx.x & 63;
    const size_t rowbase = (size_t)b * S_;
    const float* kbase = K + rowbase * AD + h * HD;
    const float* vbase = V + rowbase * AD + h * HD;
    const float scale = 0.17677669529663688f;  // 1/sqrt(32): monotone, selection-safe

    for (int r = 0; r < 4; ++r) {
        const int qrow = blockIdx.y * 16 + wid * 4 + r;
        const float* qp = Q + (rowbase + qrow) * AD + h * HD;
        float qreg[HD];
        #pragma unroll
        for (int d = 0; d < HD; ++d) qreg[d] = qp[d];

        // lane owns k-indices {lane + 64*t : t=0..31}
        float sc[32];
        #pragma unroll
        for (int t = 0; t < 32; ++t) {
            const float* kp = kbase + (size_t)(t * 64 + lane) * AD;
            float s = 0.f;
            #pragma unroll
            for (int d = 0; d < HD; ++d) s = fmaf(qreg[d], kp[d], s);
            sc[t] = s * scale;
        }

        unsigned consumed = 0u;
        float selv = 0.f; int selj = 0;   // lane i (<32) ends holding winner i
        for (int i = 0; i < TK; ++i) {
            float bv = -3.0e38f; int gj = 0x7FFFFFFF;
            #pragma unroll
            for (int t = 0; t < 32; ++t) {
                float vv = sc[t];
                bool alive = ((consumed >> t) & 1u) == 0u;
                if (alive && vv > bv) { bv = vv; gj = t * 64 + lane; }
            }
            #pragma unroll
            for (int off = 1; off < 64; off <<= 1) {
                float ov = __shfl_xor(bv, off);
                int   oj = __shfl_xor(gj, off);
                if (ov > bv || (ov == bv && oj < gj)) { bv = ov; gj = oj; }
            }
            if ((gj & 63) == lane) consumed |= (1u << (gj >> 6));
            if (lane == i) { selv = bv; selj = gj; }
        }

        // softmax over the 32 selected (max is winner 0)
        float m = __shfl(selv, 0);
        float e = (lane < TK) ? expf(selv - m) : 0.f;
        float ssum = e;
        #pragma unroll
        for (int off = 1; off < 64; off <<= 1) ssum += __shfl_xor(ssum, off);
        float w = e / ssum;

        // out[d] = sum_i w_i * v[idx_i][d]; lanes split the i-range in halves
        float oacc = 0.f;
        const int dd = lane & 31;
        const int half = lane >> 5;
        #pragma unroll
        for (int u = 0; u < 16; ++u) {
            int i = half * 16 + u;
            float wi = __shfl(w, i);
            int   ji = __shfl(selj, i);
            oacc = fmaf(wi, vbase[(size_t)ji * AD + dd], oacc);
        }
        oacc += __shfl_down(oacc, 32);
        if (lane < HD) O[(rowbase + qrow) * AD + h * HD + lane] = oacc;
    }
}

__global__ __launch_bounds__(256)
void concat_kernel()
{
    int i = blockIdx.x * 256 + threadIdx.x;   // over 8192*256
    int row = i >> 8, c = i & 255;
    float v = (c < AD) ? g_ws[OFF_T + row * AD + c]
                       : g_ws[OFF_SB + row * AD + (c - AD)];
    g_ws[OFF_CAT + i] = v;
}

__global__ __launch_bounds__(256)
void fuse_kernel(float* __restrict__ out)
{
    int i = blockIdx.x * 256 + threadIdx.x;   // over 8192*128
    float g = g_ws[OFF_Q + i];
    float f = g_ws[OFF_K + i];
    out[i] = f / (1.0f + expf(-g));           // f * sigmoid(g)
}

extern "C" void kernel_launch(void* const* d_in, const int* in_sizes, int n_in,
                              void* d_out, int out_size, void* d_ws, size_t ws_size,
                              hipStream_t stream)
{
    (void)in_sizes; (void)n_in; (void)d_ws; (void)ws_size; (void)out_size;
    const float* x      = (const float*)d_in[0];
    const float* tp_w   = (const float*)d_in[1];
    const float* tp_b   = (const float*)d_in[2];
    const float* sp_w   = (const float*)d_in[3];
    const float* sp_b   = (const float*)d_in[4];
    const float* gate_w = (const float*)d_in[21];
    const float* gate_b = (const float*)d_in[22];
    const float* fus_w  = (const float*)d_in[23];
    const float* fus_b  = (const float*)d_in[24];

    dim3 gl(128, 2);
    for (int br = 0; br < 2; ++br) {
        const float* pw = br ? sp_w : tp_w;
        const float* pb = br ? sp_b : tp_b;
        int base = 5 + br * 8;
        const float* qw = (const float*)d_in[base + 0];
        const float* qb = (const float*)d_in[base + 1];
        const float* kw = (const float*)d_in[base + 2];
        const float* kb = (const float*)d_in[base + 3];
        const float* vw = (const float*)d_in[base + 4];
        const float* vb = (const float*)d_in[base + 5];
        const float* ow = (const float*)d_in[base + 6];
        const float* ob = (const float*)d_in[base + 7];

        lin_kernel<256><<<gl, 256, 0, stream>>>(x, 0, pw, pb, OFF_PROJ);
        lin_kernel<128><<<gl, 256, 0, stream>>>(nullptr, OFF_PROJ, qw, qb, OFF_Q);
        lin_kernel<128><<<gl, 256, 0, stream>>>(nullptr, OFF_PROJ, kw, kb, OFF_K);
        lin_kernel<128><<<gl, 256, 0, stream>>>(nullptr, OFF_PROJ, vw, vb, OFF_V);
        attn_kernel<<<dim3(16, 128), 256, 0, stream>>>(OFF_Q, OFF_K, OFF_V, OFF_ATT);
        lin_kernel<128><<<gl, 256, 0, stream>>>(nullptr, OFF_ATT, ow, ob,
                                                br ? OFF_SB : OFF_T);
    }
    concat_kernel<<<8192, 256, 0, stream>>>();
    lin_kernel<256><<<gl, 256, 0, stream>>>(nullptr, OFF_CAT, gate_w, gate_b, OFF_Q);
    lin_kernel<256><<<gl, 256, 0, stream>>>(nullptr, OFF_CAT, fus_w, fus_b, OFF_K);
    fuse_kernel<<<4096, 256, 0, stream>>>((float*)d_out);
}